// Round 2
// baseline (56957.703 us; speedup 1.0000x reference)
//
#include <hip/hip_runtime.h>
#include <hip/hip_cooperative_groups.h>
#include <math.h>

namespace cg = cooperative_groups;

#define B_ 64
#define T_ 512
#define F_ 128
#define H_ 512

// ---------------------------------------------------------------------------
// One-time input transpose: input[b][t][f] -> xT[t][f][b]
// ---------------------------------------------------------------------------
__global__ void transpose_x(const float* __restrict__ in, float* __restrict__ xT) {
    __shared__ float tile[F_][B_ + 1];
    const int t   = blockIdx.x;
    const int tid = threadIdx.x;
    for (int idx = tid; idx < B_ * F_; idx += blockDim.x) {
        int bb = idx >> 7;
        int f  = idx & (F_ - 1);
        tile[f][bb] = in[(size_t)bb * T_ * F_ + (size_t)t * F_ + f];
    }
    __syncthreads();
    for (int idx = tid; idx < B_ * F_; idx += blockDim.x) {
        int f  = idx >> 6;
        int bb = idx & (B_ - 1);
        xT[(size_t)t * F_ * B_ + (size_t)f * B_ + bb] = tile[f][bb];
    }
}

__device__ __forceinline__ float sigmoid_(float x) { return 1.0f / (1.0f + expf(-x)); }

// Async 16 KB chunk stage: 256 threads x 4 sweeps x 16 B -> LDS, via DMA
// (global_load_lds). LDS dest is wave-uniform base + lane*16; our linear
// tid*16 layout satisfies that exactly.
__device__ __forceinline__ void stage16k(const float* __restrict__ src,
                                         float* lds_base, int tid) {
#pragma unroll
    for (int sweep = 0; sweep < 4; ++sweep) {
        const int off = sweep * 4096 + tid * 16;  // bytes
        __builtin_amdgcn_global_load_lds(
            (const __attribute__((address_space(1))) void*)((const char*)src + off),
            (__attribute__((address_space(3))) void*)((char*)lds_base + off),
            16, 0, 0);
    }
}

// ---------------------------------------------------------------------------
// Persistent layer-pipelined LSTM scan, K-split-within-block version.
// Grid = 384 blocks x 256 threads. Block (layer = bid>>7, cb = bid&127) owns
// state columns [cb*4, cb*4+4). Thread (b = tid&63, w = tid>>6):
//   - compute phase: 16 partial accumulators (4 cols x 4 gates) over this
//     wave's K-quarter (rows w*16..w*16+16 of every 64-row LDS chunk).
//     x/h stream values come from LDS (staged per block, double-buffered,
//     async DMA); weights come from the scalar path (wave-uniform float4
//     rows -> s_load_dwordx4; safe: weights are read-only).
//   - reduce phase: 16 KB LDS cross-wave reduction; thread (b,w) finalizes
//     column cb*4+w (gates + c-state in register) and stores h.
// One grid.sync per global step; layer l processes t = s - l.
// ---------------------------------------------------------------------------
__global__ void __launch_bounds__(256) lstm_scan(
    const float* __restrict__ xT, float* __restrict__ hb, float* __restrict__ h1s,
    float* __restrict__ out,
    const float* __restrict__ Wih0, const float* __restrict__ Whh0,
    const float* __restrict__ bih0, const float* __restrict__ bhh0,
    const float* __restrict__ Wih1, const float* __restrict__ Whh1,
    const float* __restrict__ bih1, const float* __restrict__ bhh1,
    const float* __restrict__ Wih2, const float* __restrict__ Whh2,
    const float* __restrict__ bih2, const float* __restrict__ bhh2,
    const float* __restrict__ fcW1, const float* __restrict__ fcb1,
    const float* __restrict__ fcW2, const float* __restrict__ fcb2) {
    cg::grid_group grid = cg::this_grid();

    __shared__ float sbuf[2][4096];      // 2 x 16 KB staging chunks [64 rows][64 b]
    __shared__ float red[4][4][4][64];   // [wave][col][gate][b] partials, 16 KB

    const float* WihA[3] = {Wih0, Wih1, Wih2};
    const float* WhhA[3] = {Whh0, Whh1, Whh2};
    const float* bihA[3] = {bih0, bih1, bih2};
    const float* bhhA[3] = {bhh0, bhh1, bhh2};

    const int tid   = threadIdx.x;
    const int layer = blockIdx.x >> 7;                 // 0..2
    const int cb    = blockIdx.x & 127;                // 0..127
    const int b     = tid & 63;                        // lane = batch row
    const int w     = __builtin_amdgcn_readfirstlane(tid >> 6);  // wave 0..3
    const int w16   = w * 16;
    const int c0    = cb * 4;                          // first owned column
    const int Kx    = (layer == 0) ? F_ : H_;          // input-stream length
    const int ncx   = Kx >> 6;                         // x chunks (2 or 8)
    const int nc    = ncx + 8;                         // + 8 h chunks

    const float* wih = WihA[layer];
    const float* whh = WhhA[layer];

    // Finalize-phase constants: this thread owns column c0+w.
    const int mycol = c0 + w;
    float bias[4];
#pragma unroll
    for (int g = 0; g < 4; ++g)
        bias[g] = bihA[layer][g * 512 + mycol] + bhhA[layer][g * 512 + mycol];

    float* hb_l = hb + (size_t)layer * 2 * H_ * B_;
    const float* hb_in = (layer == 0) ? xT
                         : hb + (size_t)(layer - 1) * 2 * H_ * B_;

    float c_reg = 0.0f;

    for (int s = 0; s < T_ + 2; ++s) {
        const int t = s - layer;
        if (t >= 0 && t < T_) {
            const int p_out  = t & 1;
            const int p_prev = (t + 1) & 1;
            const float* xs = (layer == 0)
                                  ? (xT + (size_t)t * F_ * B_)
                                  : (hb_in + (size_t)p_out * H_ * B_);
            const float* hp = hb_l + (size_t)p_prev * H_ * B_;

            float pa[4][4];
#pragma unroll
            for (int c4 = 0; c4 < 4; ++c4)
#pragma unroll
                for (int g = 0; g < 4; ++g) pa[c4][g] = 0.0f;

            // issue chunk 0 DMA
            stage16k(xs, &sbuf[0][0], tid);

            for (int c = 0; c < nc; ++c) {
                __syncthreads();   // drains vmcnt -> chunk c landed, buffers free
                if (c + 1 < nc) {
                    const int cn = c + 1;
                    const float* src = (cn < ncx) ? (xs + (size_t)cn * 4096)
                                                  : (hp + (size_t)(cn - ncx) * 4096);
                    stage16k(src, &sbuf[cn & 1][0], tid);
                }
                const bool is_x   = (c < ncx);
                const float* wb   = is_x ? wih : whh;
                const int rowlen  = is_x ? Kx : H_;
                const int koff0   = c * 64 + w16 - (is_x ? 0 : Kx);
                const float* lb   = &sbuf[c & 1][w16 * 64 + b];
#pragma unroll
                for (int kk = 0; kk < 16; kk += 4) {
                    const float x0 = lb[(kk + 0) << 6];
                    const float x1 = lb[(kk + 1) << 6];
                    const float x2 = lb[(kk + 2) << 6];
                    const float x3 = lb[(kk + 3) << 6];
#pragma unroll
                    for (int c4 = 0; c4 < 4; ++c4) {
#pragma unroll
                        for (int g = 0; g < 4; ++g) {
                            const float4 wv = *(const float4*)(
                                wb + (size_t)(g * 512 + c0 + c4) * rowlen + (koff0 + kk));
                            pa[c4][g] = fmaf(wv.x, x0,
                                        fmaf(wv.y, x1,
                                        fmaf(wv.z, x2,
                                        fmaf(wv.w, x3, pa[c4][g]))));
                        }
                    }
                }
            }

            // cross-wave K reduction
#pragma unroll
            for (int c4 = 0; c4 < 4; ++c4)
#pragma unroll
                for (int g = 0; g < 4; ++g) red[w][c4][g][b] = pa[c4][g];
            __syncthreads();

            float a[4];
#pragma unroll
            for (int g = 0; g < 4; ++g)
                a[g] = bias[g] + red[0][w][g][b] + red[1][w][g][b] +
                       red[2][w][g][b] + red[3][w][g][b];

            const float ig = sigmoid_(a[0]);
            const float fg = sigmoid_(a[1]);
            const float gg = tanhf(a[2]);
            const float og = sigmoid_(a[3]);
            c_reg = fg * c_reg + ig * gg;
            const float hv = og * tanhf(c_reg);
            hb_l[(size_t)p_out * H_ * B_ + (size_t)mycol * B_ + b] = hv;
        }
        grid.sync();
    }

    // ---- FC head
    const float* h2 = hb + (size_t)(2 * 2 + 1) * H_ * B_;  // layer 2, parity 1
    if (blockIdx.x < 64 && tid < 64) {
        const int c  = blockIdx.x;
        const int bb = tid;
        float acc = fcb1[c];
#pragma unroll 8
        for (int k = 0; k < H_; ++k)
            acc = fmaf(fcW1[(size_t)c * H_ + k], h2[(size_t)k * B_ + bb], acc);
        h1s[c * B_ + bb] = fmaxf(acc, 0.0f);
    }
    grid.sync();
    if (blockIdx.x == 0 && tid < 64) {
        const int bb = tid;
        float acc = fcb2[0];
#pragma unroll
        for (int c = 0; c < 64; ++c)
            acc = fmaf(fcW2[c], h1s[c * B_ + bb], acc);
        out[bb] = fmaxf(acc, 0.0f);
    }
}

// ---------------------------------------------------------------------------
extern "C" void kernel_launch(void* const* d_in, const int* in_sizes, int n_in,
                              void* d_out, int out_size, void* d_ws, size_t ws_size,
                              hipStream_t stream) {
    const float* in    = (const float*)d_in[0];
    const float* Wih0  = (const float*)d_in[1];
    const float* Whh0  = (const float*)d_in[2];
    const float* bih0  = (const float*)d_in[3];
    const float* bhh0  = (const float*)d_in[4];
    const float* Wih1  = (const float*)d_in[5];
    const float* Whh1  = (const float*)d_in[6];
    const float* bih1  = (const float*)d_in[7];
    const float* bhh1  = (const float*)d_in[8];
    const float* Wih2  = (const float*)d_in[9];
    const float* Whh2  = (const float*)d_in[10];
    const float* bih2  = (const float*)d_in[11];
    const float* bhh2  = (const float*)d_in[12];
    const float* fcW1  = (const float*)d_in[13];
    const float* fcb1  = (const float*)d_in[14];
    const float* fcW2  = (const float*)d_in[15];
    const float* fcb2  = (const float*)d_in[16];
    float* outp = (float*)d_out;

    float* ws  = (float*)d_ws;
    float* xT  = ws;                                   // [T][F][B]
    float* hbf = xT + (size_t)T_ * F_ * B_;            // [3][2][H][B]
    float* h1s = hbf + (size_t)3 * 2 * H_ * B_;        // [64][64]

    hipMemsetAsync(hbf, 0, (size_t)3 * 2 * H_ * B_ * sizeof(float), stream);

    transpose_x<<<dim3(T_), dim3(256), 0, stream>>>(in, xT);

    void* args[] = {
        (void*)&xT, (void*)&hbf, (void*)&h1s, (void*)&outp,
        (void*)&Wih0, (void*)&Whh0, (void*)&bih0, (void*)&bhh0,
        (void*)&Wih1, (void*)&Whh1, (void*)&bih1, (void*)&bhh1,
        (void*)&Wih2, (void*)&Whh2, (void*)&bih2, (void*)&bhh2,
        (void*)&fcW1, (void*)&fcb1, (void*)&fcW2, (void*)&fcb2};
    hipLaunchCooperativeKernel((void*)lstm_scan, dim3(384), dim3(256), args, 0, stream);
}

// Round 3
// 42333.099 us; speedup vs baseline: 1.3455x; 1.3455x over previous
//
#include <hip/hip_runtime.h>
#include <math.h>

#define B_ 64
#define T_ 512
#define F_ 128
#define H_ 512
#define NBLK 384

// ---------------------------------------------------------------------------
// One-time input transpose: input[b][t][f] -> xT[t][f][b]
// ---------------------------------------------------------------------------
__global__ void transpose_x(const float* __restrict__ in, float* __restrict__ xT) {
    __shared__ float tile[F_][B_ + 1];
    const int t   = blockIdx.x;
    const int tid = threadIdx.x;
    for (int idx = tid; idx < B_ * F_; idx += blockDim.x) {
        int bb = idx >> 7;
        int f  = idx & (F_ - 1);
        tile[f][bb] = in[(size_t)bb * T_ * F_ + (size_t)t * F_ + f];
    }
    __syncthreads();
    for (int idx = tid; idx < B_ * F_; idx += blockDim.x) {
        int f  = idx >> 6;
        int bb = idx & (B_ - 1);
        xT[(size_t)t * F_ * B_ + (size_t)f * B_ + bb] = tile[f][bb];
    }
}

__device__ __forceinline__ float sigmoid_(float x) { return 1.0f / (1.0f + expf(-x)); }

// Async 16 KB chunk stage via DMA (global_load_lds), 256 threads x 4 x 16 B.
__device__ __forceinline__ void stage16k(const float* __restrict__ src,
                                         float* lds_base, int tid) {
#pragma unroll
    for (int sweep = 0; sweep < 4; ++sweep) {
        const int off = sweep * 4096 + tid * 16;  // bytes
        __builtin_amdgcn_global_load_lds(
            (const __attribute__((address_space(1))) void*)((const char*)src + off),
            (__attribute__((address_space(3))) void*)((char*)lds_base + off),
            16, 0, 0);
    }
}

// ---------------------------------------------------------------------------
// Custom grid barrier: no serialized RMWs.
//   arrive: per-block relaxed agent store to its own 64B-strided slot
//           (preceded by one release fence -> wbl2 pushes h to device scope)
//   aggregate: block 0's threads poll all slots in parallel
//   broadcast: single `go` word, polled read-only by each block's tid 0
//   acquire fence (inv) + __syncthreads on exit
// Slots/go are monotonically increasing epochs (no reset, no ABA).
// ---------------------------------------------------------------------------
__device__ __forceinline__ void gbar(int* __restrict__ slots, int* __restrict__ go,
                                     int bid, int tid, int e) {
    __syncthreads();  // all waves' stores vmcnt-drained to L2
    if (tid == 0) {
        __builtin_amdgcn_fence(__ATOMIC_RELEASE, "agent");  // buffer_wbl2 sc1
        __hip_atomic_store(&slots[bid * 16], e, __ATOMIC_RELAXED,
                           __HIP_MEMORY_SCOPE_AGENT);
    }
    if (bid == 0) {
        for (int s2 = tid; s2 < NBLK; s2 += 256)
            while (__hip_atomic_load(&slots[s2 * 16], __ATOMIC_RELAXED,
                                     __HIP_MEMORY_SCOPE_AGENT) < e)
                __builtin_amdgcn_s_sleep(1);
        __syncthreads();
        if (tid == 0)
            __hip_atomic_store(go, e, __ATOMIC_RELAXED, __HIP_MEMORY_SCOPE_AGENT);
    } else if (tid == 0) {
        while (__hip_atomic_load(go, __ATOMIC_RELAXED,
                                 __HIP_MEMORY_SCOPE_AGENT) < e)
            __builtin_amdgcn_s_sleep(1);
    }
    if (tid == 0)
        __builtin_amdgcn_fence(__ATOMIC_ACQUIRE, "agent");  // buffer_inv sc1
    __syncthreads();
}

// ---------------------------------------------------------------------------
// Persistent layer-pipelined LSTM scan (R2 compute structure, custom barrier).
// ---------------------------------------------------------------------------
__global__ void __launch_bounds__(256) lstm_scan(
    const float* __restrict__ xT, float* __restrict__ hb, float* __restrict__ h1s,
    float* __restrict__ out, int* __restrict__ bar_slots, int* __restrict__ bar_go,
    const float* __restrict__ Wih0, const float* __restrict__ Whh0,
    const float* __restrict__ bih0, const float* __restrict__ bhh0,
    const float* __restrict__ Wih1, const float* __restrict__ Whh1,
    const float* __restrict__ bih1, const float* __restrict__ bhh1,
    const float* __restrict__ Wih2, const float* __restrict__ Whh2,
    const float* __restrict__ bih2, const float* __restrict__ bhh2,
    const float* __restrict__ fcW1, const float* __restrict__ fcb1,
    const float* __restrict__ fcW2, const float* __restrict__ fcb2) {
    __shared__ float sbuf[2][4096];      // 2 x 16 KB staging chunks [64 k][64 b]
    __shared__ float red[4][4][4][64];   // [wave][col][gate][b] partials

    const float* WihA[3] = {Wih0, Wih1, Wih2};
    const float* WhhA[3] = {Whh0, Whh1, Whh2};
    const float* bihA[3] = {bih0, bih1, bih2};
    const float* bhhA[3] = {bhh0, bhh1, bhh2};

    const int tid   = threadIdx.x;
    const int bid   = blockIdx.x;
    const int layer = bid >> 7;                        // 0..2
    const int cb    = bid & 127;                       // 0..127
    const int b     = tid & 63;                        // lane = batch row
    const int w     = __builtin_amdgcn_readfirstlane(tid >> 6);  // wave 0..3
    const int w16   = w * 16;
    const int c0    = cb * 4;
    const int Kx    = (layer == 0) ? F_ : H_;
    const int ncx   = Kx >> 6;                         // 2 or 8
    const int nc    = ncx + 8;

    const float* wih = WihA[layer];
    const float* whh = WhhA[layer];

    const int mycol = c0 + w;
    float bias[4];
#pragma unroll
    for (int g = 0; g < 4; ++g)
        bias[g] = bihA[layer][g * 512 + mycol] + bhhA[layer][g * 512 + mycol];

    float* hb_l = hb + (size_t)layer * 2 * H_ * B_;
    const float* hb_in = (layer == 0) ? xT
                         : hb + (size_t)(layer - 1) * 2 * H_ * B_;

    float c_reg = 0.0f;

    for (int s = 0; s < T_ + 2; ++s) {
        const int t = s - layer;
        if (t >= 0 && t < T_) {
            const int p_out  = t & 1;
            const int p_prev = (t + 1) & 1;
            const float* xs = (layer == 0)
                                  ? (xT + (size_t)t * F_ * B_)
                                  : (hb_in + (size_t)p_out * H_ * B_);
            const float* hp = hb_l + (size_t)p_prev * H_ * B_;

            float pa[4][4];
#pragma unroll
            for (int c4 = 0; c4 < 4; ++c4)
#pragma unroll
                for (int g = 0; g < 4; ++g) pa[c4][g] = 0.0f;

            stage16k(xs, &sbuf[0][0], tid);

            for (int c = 0; c < nc; ++c) {
                __syncthreads();   // chunk c landed, buffers free
                if (c + 1 < nc) {
                    const int cn = c + 1;
                    const float* src = (cn < ncx) ? (xs + (size_t)cn * 4096)
                                                  : (hp + (size_t)(cn - ncx) * 4096);
                    stage16k(src, &sbuf[cn & 1][0], tid);
                }
                const bool is_x   = (c < ncx);
                const float* wb   = is_x ? wih : whh;
                const int rowlen  = is_x ? Kx : H_;
                const int koff0   = c * 64 + w16 - (is_x ? 0 : Kx);
                const float* lb   = &sbuf[c & 1][w16 * 64 + b];
#pragma unroll
                for (int kk = 0; kk < 16; kk += 4) {
                    const float x0 = lb[(kk + 0) << 6];
                    const float x1 = lb[(kk + 1) << 6];
                    const float x2 = lb[(kk + 2) << 6];
                    const float x3 = lb[(kk + 3) << 6];
#pragma unroll
                    for (int c4 = 0; c4 < 4; ++c4) {
#pragma unroll
                        for (int g = 0; g < 4; ++g) {
                            const float4 wv = *(const float4*)(
                                wb + (size_t)(g * 512 + c0 + c4) * rowlen + (koff0 + kk));
                            pa[c4][g] = fmaf(wv.x, x0,
                                        fmaf(wv.y, x1,
                                        fmaf(wv.z, x2,
                                        fmaf(wv.w, x3, pa[c4][g]))));
                        }
                    }
                }
            }

            // cross-wave K reduction
#pragma unroll
            for (int c4 = 0; c4 < 4; ++c4)
#pragma unroll
                for (int g = 0; g < 4; ++g) red[w][c4][g][b] = pa[c4][g];
            __syncthreads();

            float a[4];
#pragma unroll
            for (int g = 0; g < 4; ++g)
                a[g] = bias[g] + red[0][w][g][b] + red[1][w][g][b] +
                       red[2][w][g][b] + red[3][w][g][b];

            const float ig = sigmoid_(a[0]);
            const float fg = sigmoid_(a[1]);
            const float gg = tanhf(a[2]);
            const float og = sigmoid_(a[3]);
            c_reg = fg * c_reg + ig * gg;
            const float hv = og * tanhf(c_reg);
            hb_l[(size_t)p_out * H_ * B_ + (size_t)mycol * B_ + b] = hv;
        }
        gbar(bar_slots, bar_go, bid, tid, s + 1);
    }

    // ---- FC head
    const float* h2 = hb + (size_t)(2 * 2 + 1) * H_ * B_;  // layer 2, parity 1
    if (bid < 64 && tid < 64) {
        const int c  = bid;
        const int bb = tid;
        float acc = fcb1[c];
#pragma unroll 8
        for (int k = 0; k < H_; ++k)
            acc = fmaf(fcW1[(size_t)c * H_ + k], h2[(size_t)k * B_ + bb], acc);
        h1s[c * B_ + bb] = fmaxf(acc, 0.0f);
    }
    gbar(bar_slots, bar_go, bid, tid, T_ + 3);
    if (bid == 0 && tid < 64) {
        const int bb = tid;
        float acc = fcb2[0];
#pragma unroll
        for (int c = 0; c < 64; ++c)
            acc = fmaf(fcW2[c], h1s[c * B_ + bb], acc);
        out[bb] = fmaxf(acc, 0.0f);
    }
}

// ---------------------------------------------------------------------------
extern "C" void kernel_launch(void* const* d_in, const int* in_sizes, int n_in,
                              void* d_out, int out_size, void* d_ws, size_t ws_size,
                              hipStream_t stream) {
    const float* in    = (const float*)d_in[0];
    const float* Wih0  = (const float*)d_in[1];
    const float* Whh0  = (const float*)d_in[2];
    const float* bih0  = (const float*)d_in[3];
    const float* bhh0  = (const float*)d_in[4];
    const float* Wih1  = (const float*)d_in[5];
    const float* Whh1  = (const float*)d_in[6];
    const float* bih1  = (const float*)d_in[7];
    const float* bhh1  = (const float*)d_in[8];
    const float* Wih2  = (const float*)d_in[9];
    const float* Whh2  = (const float*)d_in[10];
    const float* bih2  = (const float*)d_in[11];
    const float* bhh2  = (const float*)d_in[12];
    const float* fcW1  = (const float*)d_in[13];
    const float* fcb1  = (const float*)d_in[14];
    const float* fcW2  = (const float*)d_in[15];
    const float* fcb2  = (const float*)d_in[16];
    float* outp = (float*)d_out;

    float* ws  = (float*)d_ws;
    float* xT  = ws;                                   // [T][F][B]      16 MB
    float* hbf = xT + (size_t)T_ * F_ * B_;            // [3][2][H][B]  768 KB
    float* h1s = hbf + (size_t)3 * 2 * H_ * B_;        // [64][64]       16 KB
    int*   bar = (int*)(h1s + 64 * 64);                // slots + go
    int*   bar_slots = bar;                            // NBLK * 16 ints
    int*   bar_go    = bar + NBLK * 16;                // 1 int

    // zero h buffers + FC scratch + barrier state (ws is poisoned each call)
    hipMemsetAsync(hbf, 0,
                   ((size_t)3 * 2 * H_ * B_ + 64 * 64 + NBLK * 16 + 16) * sizeof(float),
                   stream);

    transpose_x<<<dim3(T_), dim3(256), 0, stream>>>(in, xT);

    void* args[] = {
        (void*)&xT, (void*)&hbf, (void*)&h1s, (void*)&outp,
        (void*)&bar_slots, (void*)&bar_go,
        (void*)&Wih0, (void*)&Whh0, (void*)&bih0, (void*)&bhh0,
        (void*)&Wih1, (void*)&Whh1, (void*)&bih1, (void*)&bhh1,
        (void*)&Wih2, (void*)&Whh2, (void*)&bih2, (void*)&bhh2,
        (void*)&fcW1, (void*)&fcb1, (void*)&fcW2, (void*)&fcb2};
    hipLaunchCooperativeKernel((void*)lstm_scan, dim3(NBLK), dim3(256), args, 0, stream);
}

// Round 6
// 37550.406 us; speedup vs baseline: 1.5168x; 1.1274x over previous
//
#include <hip/hip_runtime.h>
#include <math.h>

#define B_ 64
#define T_ 512
#define F_ 128
#define H_ 512
#define NBLK 384
#define SPIN_MAX (1 << 23)

// ---------------------------------------------------------------------------
// One-time input transpose: input[b][t][f] -> xT[t][f][b]
// ---------------------------------------------------------------------------
__global__ void transpose_x(const float* __restrict__ in, float* __restrict__ xT) {
    __shared__ float tile[F_][B_ + 1];
    const int t   = blockIdx.x;
    const int tid = threadIdx.x;
    for (int idx = tid; idx < B_ * F_; idx += blockDim.x) {
        int bb = idx >> 7;
        int f  = idx & (F_ - 1);
        tile[f][bb] = in[(size_t)bb * T_ * F_ + (size_t)t * F_ + f];
    }
    __syncthreads();
    for (int idx = tid; idx < B_ * F_; idx += blockDim.x) {
        int f  = idx >> 6;
        int bb = idx & (B_ - 1);
        xT[(size_t)t * F_ * B_ + (size_t)f * B_ + bb] = tile[f][bb];
    }
}

__device__ __forceinline__ float sigmoid_(float x) { return 1.0f / (1.0f + expf(-x)); }

// Device-coherent 4B ops via the compiler's blessed path (relaxed agent-scope
// atomics -> sc1-coherent point-to-point, no cache-walk fences). ALL h-buffer
// traffic uses these; weights/xT stay on the normal cached path.
__device__ __forceinline__ float loadc(const float* p) {
    return __hip_atomic_load(p, __ATOMIC_RELAXED, __HIP_MEMORY_SCOPE_AGENT);
}
__device__ __forceinline__ void storec(float* p, float v) {
    __hip_atomic_store(p, v, __ATOMIC_RELAXED, __HIP_MEMORY_SCOPE_AGENT);
}

// ---------------------------------------------------------------------------
// Segment dot: this wave's K-quarter of one stream segment (x or h) against
// 16 W rows (4 owned cols x 4 gates). Stream loads are lane-coalesced
// (lane = b), double-buffered 16-deep. Weight addresses are fully
// wave-uniform inline expressions -> scalar s_load path (SGPR results, no
// VGPR address cost).
// ---------------------------------------------------------------------------
template <bool COH>
__device__ __forceinline__ void seg_dot(const float* __restrict__ seg,
                                        const float* __restrict__ wb,
                                        const int rowlen, const int segq,
                                        const int w, const int b, const int c0,
                                        float pa[4][4]) {
    const int k0  = w * segq;          // wave's quarter start
    const int nch = segq >> 4;         // 16-k chunks in quarter (2 or 8)
    const float* sp0 = seg + (size_t)k0 * 64 + b;

    float va[16], vb2[16];
    auto load16 = [&](float* v, int c) {
        const float* sp = sp0 + (size_t)c * 16 * 64;
#pragma unroll
        for (int i = 0; i < 16; ++i)
            v[i] = COH ? loadc(sp + i * 64) : sp[i * 64];
    };
    auto fma16 = [&](const float* v, int c) {
        const int kbase = k0 + c * 16;
#pragma unroll
        for (int kk = 0; kk < 16; kk += 4) {
#pragma unroll
            for (int c4 = 0; c4 < 4; ++c4) {
#pragma unroll
                for (int g = 0; g < 4; ++g) {
                    const float4 wv = *(const float4*)(
                        wb + (size_t)(g * 512 + c0 + c4) * rowlen + kbase + kk);
                    pa[c4][g] = fmaf(wv.x, v[kk + 0],
                                 fmaf(wv.y, v[kk + 1],
                                  fmaf(wv.z, v[kk + 2],
                                   fmaf(wv.w, v[kk + 3], pa[c4][g]))));
                }
            }
        }
    };
    load16(va, 0);
    for (int c = 0; c < nch; ++c) {
        float* cur = (c & 1) ? vb2 : va;
        float* nxt = (c & 1) ? va : vb2;
        if (c + 1 < nch) load16(nxt, c + 1);
        fma16(cur, c);
    }
}

// ---------------------------------------------------------------------------
// Fence-free grid barrier with BOUNDED spins (a broken barrier produces a
// wrong answer, never a hang). vmcnt drain first (h stores reach the
// coherence point), arrive-store to own slot, block 0 aggregates in parallel
// and broadcasts `go`; others poll read-only. Monotone epochs.
// ---------------------------------------------------------------------------
__device__ __forceinline__ void gbar(int* __restrict__ slots, int* __restrict__ go,
                                     int bid, int tid, int e) {
    asm volatile("s_waitcnt vmcnt(0) lgkmcnt(0)" ::: "memory");
    __syncthreads();
    if (tid == 0)
        __hip_atomic_store(&slots[bid * 16], e, __ATOMIC_RELAXED,
                           __HIP_MEMORY_SCOPE_AGENT);
    if (bid == 0) {
        for (int s2 = tid; s2 < NBLK; s2 += 256) {
            int guard = 0;
            while (__hip_atomic_load(&slots[s2 * 16], __ATOMIC_RELAXED,
                                     __HIP_MEMORY_SCOPE_AGENT) < e &&
                   ++guard < SPIN_MAX)
                __builtin_amdgcn_s_sleep(1);
        }
        __syncthreads();
        if (tid == 0)
            __hip_atomic_store(go, e, __ATOMIC_RELAXED, __HIP_MEMORY_SCOPE_AGENT);
    } else if (tid == 0) {
        int guard = 0;
        while (__hip_atomic_load(go, __ATOMIC_RELAXED,
                                 __HIP_MEMORY_SCOPE_AGENT) < e &&
               ++guard < SPIN_MAX)
            __builtin_amdgcn_s_sleep(1);
    }
    __syncthreads();
}

// ---------------------------------------------------------------------------
// Persistent layer-pipelined LSTM scan. Direct coherent stream loads (no LDS
// staging -- zero reuse); LDS only for the cross-wave K reduction.
// __launch_bounds__(256,2): VGPR <= 256 -> guaranteed 2 blocks/CU so the
// 384-block cooperative launch can never fail co-residency.
// ---------------------------------------------------------------------------
__global__ void __launch_bounds__(256, 2) lstm_scan(
    const float* __restrict__ xT, float* __restrict__ hb, float* __restrict__ h1s,
    float* __restrict__ out, int* __restrict__ bar_slots, int* __restrict__ bar_go,
    const float* __restrict__ Wih0, const float* __restrict__ Whh0,
    const float* __restrict__ bih0, const float* __restrict__ bhh0,
    const float* __restrict__ Wih1, const float* __restrict__ Whh1,
    const float* __restrict__ bih1, const float* __restrict__ bhh1,
    const float* __restrict__ Wih2, const float* __restrict__ Whh2,
    const float* __restrict__ bih2, const float* __restrict__ bhh2,
    const float* __restrict__ fcW1, const float* __restrict__ fcb1,
    const float* __restrict__ fcW2, const float* __restrict__ fcb2) {
    __shared__ float red[4][4][4][64];   // [wave][col][gate][b] partials

    const float* WihA[3] = {Wih0, Wih1, Wih2};
    const float* WhhA[3] = {Whh0, Whh1, Whh2};
    const float* bihA[3] = {bih0, bih1, bih2};
    const float* bhhA[3] = {bhh0, bhh1, bhh2};

    const int tid   = threadIdx.x;
    const int bid   = blockIdx.x;
    const int layer = bid >> 7;                        // 0..2 (R3 mapping)
    const int cb    = bid & 127;
    const int b     = tid & 63;
    const int w     = __builtin_amdgcn_readfirstlane(tid >> 6);  // 0..3
    const int c0    = cb * 4;

    const float* wih = WihA[layer];
    const float* whh = WhhA[layer];

    const int mycol = c0 + w;
    float bias[4];
#pragma unroll
    for (int g = 0; g < 4; ++g)
        bias[g] = bihA[layer][g * 512 + mycol] + bhhA[layer][g * 512 + mycol];

    float* hb_l = hb + (size_t)layer * 2 * H_ * B_;
    const float* hb_in = (layer == 0) ? xT
                         : hb + (size_t)(layer - 1) * 2 * H_ * B_;

    float c_reg = 0.0f;

    for (int s = 0; s < T_ + 2; ++s) {
        const int t = s - layer;
        if (t >= 0 && t < T_) {
            const int p_out  = t & 1;
            const int p_prev = (t + 1) & 1;
            const float* xs = (layer == 0)
                                  ? (xT + (size_t)t * F_ * B_)
                                  : (hb_in + (size_t)p_out * H_ * B_);
            const float* hp = hb_l + (size_t)p_prev * H_ * B_;

            float pa[4][4] = {};
            if (layer == 0) seg_dot<false>(xs, wih, F_, F_ / 4, w, b, c0, pa);
            else            seg_dot<true>(xs, wih, H_, H_ / 4, w, b, c0, pa);
            seg_dot<true>(hp, whh, H_, H_ / 4, w, b, c0, pa);

            // cross-wave K reduction
#pragma unroll
            for (int c4 = 0; c4 < 4; ++c4)
#pragma unroll
                for (int g = 0; g < 4; ++g) red[w][c4][g][b] = pa[c4][g];
            __syncthreads();

            float a[4];
#pragma unroll
            for (int g = 0; g < 4; ++g)
                a[g] = bias[g] + red[0][w][g][b] + red[1][w][g][b] +
                       red[2][w][g][b] + red[3][w][g][b];

            const float ig = sigmoid_(a[0]);
            const float fg = sigmoid_(a[1]);
            const float gg = tanhf(a[2]);
            const float og = sigmoid_(a[3]);
            c_reg = fg * c_reg + ig * gg;
            const float hv = og * tanhf(c_reg);
            storec(&hb_l[(size_t)p_out * H_ * B_ + (size_t)mycol * B_ + b], hv);
        }
        gbar(bar_slots, bar_go, bid, tid, s + 1);
    }

    // ---- FC head. h2 = layer-2 h at t=511 (parity 1), coherent reads.
    const float* h2 = hb + (size_t)(2 * 2 + 1) * H_ * B_;
    if (bid < 64) {
        float part = 0.0f;
        const float* wrow = fcW1 + (size_t)bid * H_ + w * 128;
        const float* hseg = h2 + (size_t)(w * 128) * 64 + b;
#pragma unroll 8
        for (int k = 0; k < 128; ++k)
            part = fmaf(wrow[k], loadc(hseg + (size_t)k * 64), part);
        red[w][0][0][b] = part;
        __syncthreads();
        if (tid < 64) {
            float acc = fcb1[bid] + red[0][0][0][b] + red[1][0][0][b] +
                        red[2][0][0][b] + red[3][0][0][b];
            storec(&h1s[bid * B_ + b], fmaxf(acc, 0.0f));
        }
    }
    gbar(bar_slots, bar_go, bid, tid, T_ + 3);
    if (bid == 0 && tid < 64) {
        float acc = fcb2[0];
#pragma unroll
        for (int c = 0; c < 64; ++c)
            acc = fmaf(fcW2[c], loadc(&h1s[c * B_ + tid]), acc);
        out[tid] = fmaxf(acc, 0.0f);
    }
}

// ---------------------------------------------------------------------------
extern "C" void kernel_launch(void* const* d_in, const int* in_sizes, int n_in,
                              void* d_out, int out_size, void* d_ws, size_t ws_size,
                              hipStream_t stream) {
    const float* in    = (const float*)d_in[0];
    const float* Wih0  = (const float*)d_in[1];
    const float* Whh0  = (const float*)d_in[2];
    const float* bih0  = (const float*)d_in[3];
    const float* bhh0  = (const float*)d_in[4];
    const float* Wih1  = (const float*)d_in[5];
    const float* Whh1  = (const float*)d_in[6];
    const float* bih1  = (const float*)d_in[7];
    const float* bhh1  = (const float*)d_in[8];
    const float* Wih2  = (const float*)d_in[9];
    const float* Whh2  = (const float*)d_in[10];
    const float* bih2  = (const float*)d_in[11];
    const float* bhh2  = (const float*)d_in[12];
    const float* fcW1  = (const float*)d_in[13];
    const float* fcb1  = (const float*)d_in[14];
    const float* fcW2  = (const float*)d_in[15];
    const float* fcb2  = (const float*)d_in[16];
    float* outp = (float*)d_out;

    float* ws  = (float*)d_ws;
    float* xT  = ws;                                   // [T][F][B]      16 MB
    float* hbf = xT + (size_t)T_ * F_ * B_;            // [3][2][H][B]  768 KB
    float* h1s = hbf + (size_t)3 * 2 * H_ * B_;        // [64][64]       16 KB
    int*   bar = (int*)(h1s + 64 * 64);
    int*   bar_slots = bar;                            // NBLK * 16 ints
    int*   bar_go    = bar + NBLK * 16;                // 1 int

    hipMemsetAsync(hbf, 0,
                   ((size_t)3 * 2 * H_ * B_ + 64 * 64 + NBLK * 16 + 16) * sizeof(float),
                   stream);

    transpose_x<<<dim3(T_), dim3(256), 0, stream>>>(in, xT);

    void* args[] = {
        (void*)&xT, (void*)&hbf, (void*)&h1s, (void*)&outp,
        (void*)&bar_slots, (void*)&bar_go,
        (void*)&Wih0, (void*)&Whh0, (void*)&bih0, (void*)&bhh0,
        (void*)&Wih1, (void*)&Whh1, (void*)&bih1, (void*)&bhh1,
        (void*)&Wih2, (void*)&Whh2, (void*)&bih2, (void*)&bhh2,
        (void*)&fcW1, (void*)&fcb1, (void*)&fcW2, (void*)&fcb2};
    hipLaunchCooperativeKernel((void*)lstm_scan, dim3(NBLK), dim3(256), args, 0, stream);
}

// Round 7
// 12342.345 us; speedup vs baseline: 4.6148x; 3.0424x over previous
//
#include <hip/hip_runtime.h>
#include <math.h>

#define B_ 64
#define T_ 512
#define F_ 128
#define H_ 512
#define NBLK 384
#define SPIN_MAX (1 << 23)

// ---------------------------------------------------------------------------
// One-time input transpose: input[b][t][f] -> xT[t][f][b]
// ---------------------------------------------------------------------------
__global__ void transpose_x(const float* __restrict__ in, float* __restrict__ xT) {
    __shared__ float tile[F_][B_ + 1];
    const int t   = blockIdx.x;
    const int tid = threadIdx.x;
    for (int idx = tid; idx < B_ * F_; idx += blockDim.x) {
        int bb = idx >> 7;
        int f  = idx & (F_ - 1);
        tile[f][bb] = in[(size_t)bb * T_ * F_ + (size_t)t * F_ + f];
    }
    __syncthreads();
    for (int idx = tid; idx < B_ * F_; idx += blockDim.x) {
        int f  = idx >> 6;
        int bb = idx & (B_ - 1);
        xT[(size_t)t * F_ * B_ + (size_t)f * B_ + bb] = tile[f][bb];
    }
}

__device__ __forceinline__ float sigmoid_(float x) { return 1.0f / (1.0f + expf(-x)); }

// Device-coherent 4B ops (relaxed agent-scope atomics -> sc1 point-to-point
// coherent, no cache-walk fences). All h-buffer traffic uses these.
__device__ __forceinline__ float loadc(const float* p) {
    return __hip_atomic_load(p, __ATOMIC_RELAXED, __HIP_MEMORY_SCOPE_AGENT);
}
__device__ __forceinline__ void storec(float* p, float v) {
    __hip_atomic_store(p, v, __ATOMIC_RELAXED, __HIP_MEMORY_SCOPE_AGENT);
}

// ---------------------------------------------------------------------------
// Fence-free grid barrier with bounded spins (failure -> wrong answer, never
// a hang). vmcnt drain first, arrive-store to own slot, block 0 aggregates in
// parallel and broadcasts `go`; others poll read-only. Monotone epochs.
// ---------------------------------------------------------------------------
__device__ __forceinline__ void gbar(int* __restrict__ slots, int* __restrict__ go,
                                     int bid, int tid, int e) {
    asm volatile("s_waitcnt vmcnt(0) lgkmcnt(0)" ::: "memory");
    __syncthreads();
    if (tid == 0)
        __hip_atomic_store(&slots[bid * 16], e, __ATOMIC_RELAXED,
                           __HIP_MEMORY_SCOPE_AGENT);
    if (bid == 0) {
        for (int s2 = tid; s2 < NBLK; s2 += 256) {
            int guard = 0;
            while (__hip_atomic_load(&slots[s2 * 16], __ATOMIC_RELAXED,
                                     __HIP_MEMORY_SCOPE_AGENT) < e &&
                   ++guard < SPIN_MAX)
                __builtin_amdgcn_s_sleep(1);
        }
        __syncthreads();
        if (tid == 0)
            __hip_atomic_store(go, e, __ATOMIC_RELAXED, __HIP_MEMORY_SCOPE_AGENT);
    } else if (tid == 0) {
        int guard = 0;
        while (__hip_atomic_load(go, __ATOMIC_RELAXED,
                                 __HIP_MEMORY_SCOPE_AGENT) < e &&
               ++guard < SPIN_MAX)
            __builtin_amdgcn_s_sleep(1);
    }
    __syncthreads();
}

// ---------------------------------------------------------------------------
// One LSTM step's GEMM work for this wave: 16 gate rows (4 cols x 4 gates)
// over the wave's K-quarter of [x-seg | h-seg]. Weights come from LDS
// (block-stationary, staged once -> ds_read_b128, in-order lgkmcnt, NO
// scalar-load drains). Stream comes from global, 4B lane-coalesced, 3-buffer
// pipelined 2 chunks (32 loads) ahead.
// KX = x-seg length (128 or 512); XCOH = x-seg needs coherent loads.
// ---------------------------------------------------------------------------
template <int KX, bool XCOH>
__device__ __forceinline__ void step_gemm(const float* __restrict__ xs,
                                          const float* __restrict__ hp,
                                          const float* wlds,  // LDS, addrspace known via inlining
                                          const int w, const int b,
                                          float pa[4][4]) {
    constexpr int NCX = KX / 64;       // x chunks in this wave's quarter... (KX/4)/16
    constexpr int XQ  = KX / 4;        // x-quarter length
    constexpr int NC  = (XQ >> 4) + 8; // total 16-k chunks (x-quarter + h-quarter)
    constexpr int RS  = KX + 512;      // LDS weight row stride (floats)
    (void)NCX;

    float buf[3][16];

    auto srcp = [&](int c) -> const float* {
        return (c < (XQ >> 4)) ? (xs + (size_t)(w * XQ + c * 16) * 64 + b)
                               : (hp + (size_t)(w * 128 + (c - (XQ >> 4)) * 16) * 64 + b);
    };

#pragma unroll
    for (int i = 0; i < 16; ++i) {   // prologue chunk 0
        const float* sp = srcp(0);
        buf[0][i] = (0 < (XQ >> 4) ? XCOH : true) ? loadc(sp + i * 64) : sp[i * 64];
    }
#pragma unroll
    for (int i = 0; i < 16; ++i) {   // prologue chunk 1
        const float* sp = srcp(1);
        buf[1][i] = (1 < (XQ >> 4) ? XCOH : true) ? loadc(sp + i * 64) : sp[i * 64];
    }

#pragma unroll
    for (int c = 0; c < NC; ++c) {
        if (c + 2 < NC) {
            const float* sp = srcp(c + 2);
            const bool coh = ((c + 2) < (XQ >> 4)) ? XCOH : true;
#pragma unroll
            for (int i = 0; i < 16; ++i)
                buf[(c + 2) % 3][i] = coh ? loadc(sp + i * 64) : sp[i * 64];
        }
        const int kbase = (c < (XQ >> 4)) ? (w * XQ + c * 16)
                                          : (KX + w * 128 + (c - (XQ >> 4)) * 16);
        const float* v = buf[c % 3];
#pragma unroll
        for (int kk = 0; kk < 16; kk += 4) {
#pragma unroll
            for (int r = 0; r < 16; ++r) {
                const float4 wv = *(const float4*)(wlds + r * RS + kbase + kk);
                pa[r >> 2][r & 3] = fmaf(wv.x, v[kk + 0],
                                     fmaf(wv.y, v[kk + 1],
                                      fmaf(wv.z, v[kk + 2],
                                       fmaf(wv.w, v[kk + 3], pa[r >> 2][r & 3]))));
            }
        }
    }
}

// ---------------------------------------------------------------------------
// Persistent layer-pipelined LSTM scan. Weights block-stationary in LDS
// (64 KB) + 16 KB reduction = 80 KB -> exactly 2 blocks/CU; launch_bounds
// (256,2) keeps VGPR <= 128 so 384-block co-residency is guaranteed.
// ---------------------------------------------------------------------------
__global__ void __launch_bounds__(256, 2) lstm_scan(
    const float* __restrict__ xT, float* __restrict__ hb, float* __restrict__ h1s,
    float* __restrict__ out, int* __restrict__ bar_slots, int* __restrict__ bar_go,
    const float* __restrict__ Wih0, const float* __restrict__ Whh0,
    const float* __restrict__ bih0, const float* __restrict__ bhh0,
    const float* __restrict__ Wih1, const float* __restrict__ Whh1,
    const float* __restrict__ bih1, const float* __restrict__ bhh1,
    const float* __restrict__ Wih2, const float* __restrict__ Whh2,
    const float* __restrict__ bih2, const float* __restrict__ bhh2,
    const float* __restrict__ fcW1, const float* __restrict__ fcb1,
    const float* __restrict__ fcW2, const float* __restrict__ fcb2) {
    __shared__ float wlds[16 * 1024];    // 16 gate rows x (KX+512) k, 64 KB max
    __shared__ float red[4][4][4][64];   // [wave][col][gate][b] partials, 16 KB

    const float* WihA[3] = {Wih0, Wih1, Wih2};
    const float* WhhA[3] = {Whh0, Whh1, Whh2};
    const float* bihA[3] = {bih0, bih1, bih2};
    const float* bhhA[3] = {bhh0, bhh1, bhh2};

    const int tid   = threadIdx.x;
    const int bid   = blockIdx.x;
    const int layer = bid >> 7;                        // 0..2
    const int cb    = bid & 127;
    const int b     = tid & 63;
    const int w     = __builtin_amdgcn_readfirstlane(tid >> 6);  // 0..3
    const int c0    = cb * 4;
    const int KXl   = (layer == 0) ? F_ : H_;
    const int RS    = KXl + 512;

    const float* wih = WihA[layer];
    const float* whh = WhhA[layer];

    // ---- Stage this block's 16 weight rows into LDS once (cached loads).
    // Row r = c4*4+g holds [Wih row | Whh row] for gate row g*512+c0+c4.
    for (int r = 0; r < 16; ++r) {
        const int grow = (r & 3) * 512 + c0 + (r >> 2);
        const float* src_ih = wih + (size_t)grow * KXl;
        const float* src_hh = whh + (size_t)grow * 512;
        for (int i = tid; i < RS; i += 256)
            wlds[r * RS + i] = (i < KXl) ? src_ih[i] : src_hh[i - KXl];
    }
    __syncthreads();

    const int mycol = c0 + w;
    float bias[4];
#pragma unroll
    for (int g = 0; g < 4; ++g)
        bias[g] = bihA[layer][g * 512 + mycol] + bhhA[layer][g * 512 + mycol];

    float* hb_l = hb + (size_t)layer * 2 * H_ * B_;
    const float* hb_in = (layer == 0) ? xT
                         : hb + (size_t)(layer - 1) * 2 * H_ * B_;

    float c_reg = 0.0f;

    for (int s = 0; s < T_ + 2; ++s) {
        const int t = s - layer;
        if (t >= 0 && t < T_) {
            const int p_out  = t & 1;
            const int p_prev = (t + 1) & 1;
            const float* xs = (layer == 0)
                                  ? (xT + (size_t)t * F_ * B_)
                                  : (hb_in + (size_t)p_out * H_ * B_);
            const float* hp = hb_l + (size_t)p_prev * H_ * B_;

            float pa[4][4] = {};
            if (layer == 0) step_gemm<F_, false>(xs, hp, wlds, w, b, pa);
            else            step_gemm<H_, true>(xs, hp, wlds, w, b, pa);

            // cross-wave K reduction
#pragma unroll
            for (int c4 = 0; c4 < 4; ++c4)
#pragma unroll
                for (int g = 0; g < 4; ++g) red[w][c4][g][b] = pa[c4][g];
            __syncthreads();

            float a[4];
#pragma unroll
            for (int g = 0; g < 4; ++g)
                a[g] = bias[g] + red[0][w][g][b] + red[1][w][g][b] +
                       red[2][w][g][b] + red[3][w][g][b];

            const float ig = sigmoid_(a[0]);
            const float fg = sigmoid_(a[1]);
            const float gg = tanhf(a[2]);
            const float og = sigmoid_(a[3]);
            c_reg = fg * c_reg + ig * gg;
            const float hv = og * tanhf(c_reg);
            storec(&hb_l[(size_t)p_out * H_ * B_ + (size_t)mycol * B_ + b], hv);
        }
        gbar(bar_slots, bar_go, bid, tid, s + 1);
    }

    // ---- FC head. h2 = layer-2 h at t=511 (parity 1), coherent reads.
    const float* h2 = hb + (size_t)(2 * 2 + 1) * H_ * B_;
    if (bid < 64) {
        float part = 0.0f;
        const float* wrow = fcW1 + (size_t)bid * H_ + w * 128;
        const float* hseg = h2 + (size_t)(w * 128) * 64 + b;
#pragma unroll 8
        for (int k = 0; k < 128; ++k)
            part = fmaf(wrow[k], loadc(hseg + (size_t)k * 64), part);
        red[w][0][0][b] = part;
        __syncthreads();
        if (tid < 64) {
            float acc = fcb1[bid] + red[0][0][0][b] + red[1][0][0][b] +
                        red[2][0][0][b] + red[3][0][0][b];
            storec(&h1s[bid * B_ + b], fmaxf(acc, 0.0f));
        }
    }
    gbar(bar_slots, bar_go, bid, tid, T_ + 3);
    if (bid == 0 && tid < 64) {
        float acc = fcb2[0];
#pragma unroll
        for (int c = 0; c < 64; ++c)
            acc = fmaf(fcW2[c], loadc(&h1s[c * B_ + tid]), acc);
        out[tid] = fmaxf(acc, 0.0f);
    }
}

// ---------------------------------------------------------------------------
extern "C" void kernel_launch(void* const* d_in, const int* in_sizes, int n_in,
                              void* d_out, int out_size, void* d_ws, size_t ws_size,
                              hipStream_t stream) {
    const float* in    = (const float*)d_in[0];
    const float* Wih0  = (const float*)d_in[1];
    const float* Whh0  = (const float*)d_in[2];
    const float* bih0  = (const float*)d_in[3];
    const float* bhh0  = (const float*)d_in[4];
    const float* Wih1  = (const float*)d_in[5];
    const float* Whh1  = (const float*)d_in[6];
    const float* bih1  = (const float*)d_in[7];
    const float* bhh1  = (const float*)d_in[8];
    const float* Wih2  = (const float*)d_in[9];
    const float* Whh2  = (const float*)d_in[10];
    const float* bih2  = (const float*)d_in[11];
    const float* bhh2  = (const float*)d_in[12];
    const float* fcW1  = (const float*)d_in[13];
    const float* fcb1  = (const float*)d_in[14];
    const float* fcW2  = (const float*)d_in[15];
    const float* fcb2  = (const float*)d_in[16];
    float* outp = (float*)d_out;

    float* ws  = (float*)d_ws;
    float* xT  = ws;                                   // [T][F][B]      16 MB
    float* hbf = xT + (size_t)T_ * F_ * B_;            // [3][2][H][B]  768 KB
    float* h1s = hbf + (size_t)3 * 2 * H_ * B_;        // [64][64]       16 KB
    int*   bar = (int*)(h1s + 64 * 64);
    int*   bar_slots = bar;                            // NBLK * 16 ints
    int*   bar_go    = bar + NBLK * 16;                // 1 int

    hipMemsetAsync(hbf, 0,
                   ((size_t)3 * 2 * H_ * B_ + 64 * 64 + NBLK * 16 + 16) * sizeof(float),
                   stream);

    transpose_x<<<dim3(T_), dim3(256), 0, stream>>>(in, xT);

    void* args[] = {
        (void*)&xT, (void*)&hbf, (void*)&h1s, (void*)&outp,
        (void*)&bar_slots, (void*)&bar_go,
        (void*)&Wih0, (void*)&Whh0, (void*)&bih0, (void*)&bhh0,
        (void*)&Wih1, (void*)&Whh1, (void*)&bih1, (void*)&bhh1,
        (void*)&Wih2, (void*)&Whh2, (void*)&bih2, (void*)&bhh2,
        (void*)&fcW1, (void*)&fcb1, (void*)&fcW2, (void*)&fcb2};
    hipLaunchCooperativeKernel((void*)lstm_scan, dim3(NBLK), dim3(256), args, 0, stream);
}